// Round 8
// baseline (600.644 us; speedup 1.0000x reference)
//
#include <hip/hip_runtime.h>

#define N0_ 1000000
#define N1_ 200000
#define N2_ 20000
#define N3_ 2048
#define E0_ 2000000
#define E1_ 200000
#define E2_ 20480
#define IN_ 128
#define HID_ 256
#define OUT_ 47

#define NTOT_ (N1_ + N2_ + N3_)          // 222048
#define ETOT_ (E0_ + E1_ + E2_)          // 2220480
#define MAXDEG_ 48                        // Poisson(10): P(deg>=48) ~ 1e-18

typedef unsigned short u16;
typedef unsigned int u32;
typedef __attribute__((ext_vector_type(8))) short b16x8;
typedef __attribute__((ext_vector_type(4))) float f32x4;
typedef __attribute__((ext_vector_type(4))) u16 u16x4;
typedef __attribute__((ext_vector_type(8))) u16 u16x8;

__device__ __forceinline__ u16 f2b(float f) {  // RNE fp32->bf16
  u32 u = __builtin_bit_cast(u32, f);
  return (u16)((u + 0x7FFFu + ((u >> 16) & 1u)) >> 16);
}
__device__ __forceinline__ float b2f(u16 b) {
  return __builtin_bit_cast(float, (u32)b << 16);
}

// ---------------- workspace layout (4-byte words) ----------------
static constexpr size_t OFF_CNT = 0;                       // NTOT (degree counts)
static constexpr size_t OFF_ELL = 222080;                  // NTOT*48 = 10658304
static constexpr size_t OFF_BT0 = 10880384;                // 32768  (256n x 256k bf16)
static constexpr size_t OFF_BT1 = 10913152;                // 65536  (256n x 512k bf16)
static constexpr size_t OFF_HN0 = 10978688;                // 12800000 (200000x128 bf16)
static constexpr size_t OFF_H1  = 23778688;                // 25600000 (200000x256 bf16)
static constexpr size_t OFF_HN1 = 49378688;                // 2560000  (20000x256 bf16)
static constexpr size_t OFF_H2  = 51938688;                // 2560000
// end: 54,498,688 words = 218 MB

// ---------------- one-pass ELL build + weight packs ----------------
__global__ __launch_bounds__(256) void prep(
    const int* __restrict__ src0, const int* __restrict__ dst0,
    const int* __restrict__ src1, const int* __restrict__ dst1,
    const int* __restrict__ src2, const int* __restrict__ dst2,
    const float* __restrict__ Ws0, const float* __restrict__ Wn0,
    const float* __restrict__ Ws1, const float* __restrict__ Wn1,
    int* __restrict__ cnt, int* __restrict__ ell,
    u16* __restrict__ Bt0, u16* __restrict__ Bt1) {
  int t = blockIdx.x * 256 + threadIdx.x;
  if (t < ETOT_) {
    int s, node;
    if (t < E0_) { s = src0[t]; node = dst0[t]; }
    else if (t < E0_ + E1_) { s = src1[t - E0_]; node = N1_ + dst1[t - E0_]; }
    else { s = src2[t - E0_ - E1_]; node = N1_ + N2_ + dst2[t - E0_ - E1_]; }
    int slot = atomicAdd(&cnt[node], 1);
    if (slot < MAXDEG_) ell[(size_t)node * MAXDEG_ + slot] = s;
    return;
  }
  t -= ETOT_;
  if (t < 256 * 256) {  // Bt0: [n][k], KT=256
    int n = t & 255, k = t >> 8;
    float v = (k < IN_) ? Ws0[(size_t)k * 256 + n] : Wn0[(size_t)(k - IN_) * 256 + n];
    Bt0[(size_t)n * 256 + k] = f2b(v);
    return;
  }
  t -= 256 * 256;
  if (t < 256 * 512) {  // Bt1: [n][k], KT=512
    int n = t & 255, k = t >> 8;
    float v = (k < HID_) ? Ws1[(size_t)k * 256 + n] : Wn1[(size_t)(k - HID_) * 256 + n];
    Bt1[(size_t)n * 512 + k] = f2b(v);
  }
}

// ---------------- layer-0 aggregate: fp32 source, F=128, 2 rows/wave ----------------
// lanes 0-31: even edges, 32-63: odd edges; each lane owns a 16B col slice.
// 16 row-gathers in flight per wave (8 per row).
__global__ __launch_bounds__(256) void agg0_pair(
    const float* __restrict__ h, const int* __restrict__ ell,
    const int* __restrict__ cnt, u16* __restrict__ out, int M) {
  const int pw = (blockIdx.x * 256 + threadIdx.x) >> 6;  // pair id (M even)
  const int lane = threadIdx.x & 63;
  const int r0 = pw * 2;
  if (r0 >= M) return;
  const int r1 = r0 + 1;
  const int d0 = cnt[r0], d1 = cnt[r1];
  const size_t b0 = (size_t)r0 * MAXDEG_, b1 = (size_t)r1 * MAXDEG_;
  const int half = lane >> 5;
  const int col = (lane & 31) * 4;  // fp32 col
  float x0 = 0.f, x1 = 0.f, x2 = 0.f, x3 = 0.f;
  float y0 = 0.f, y1 = 0.f, y2 = 0.f, y3 = 0.f;
  const int dmax = d0 > d1 ? d0 : d1;
  for (int i = 0; i < dmax; i += 16) {
    int ia[8], ib[8];
#pragma unroll
    for (int j = 0; j < 8; j++) {
      int k = i + 2 * j + half;
      int k0 = k < d0 ? k : d0 - 1;
      int k1 = k < d1 ? k : d1 - 1;
      ia[j] = (d0 > 0) ? ell[b0 + k0] : 0;
      ib[j] = (d1 > 0) ? ell[b1 + k1] : 0;
    }
    float4 va[8], vb[8];
#pragma unroll
    for (int j = 0; j < 8; j++)
      va[j] = *reinterpret_cast<const float4*>(&h[(size_t)ia[j] * IN_ + col]);
#pragma unroll
    for (int j = 0; j < 8; j++)
      vb[j] = *reinterpret_cast<const float4*>(&h[(size_t)ib[j] * IN_ + col]);
#pragma unroll
    for (int j = 0; j < 8; j++) {
      int k = i + 2 * j + half;
      if (k < d0) { x0 += va[j].x; x1 += va[j].y; x2 += va[j].z; x3 += va[j].w; }
      if (k < d1) { y0 += vb[j].x; y1 += vb[j].y; y2 += vb[j].z; y3 += vb[j].w; }
    }
  }
  x0 += __shfl_xor(x0, 32, 64); x1 += __shfl_xor(x1, 32, 64);
  x2 += __shfl_xor(x2, 32, 64); x3 += __shfl_xor(x3, 32, 64);
  y0 += __shfl_xor(y0, 32, 64); y1 += __shfl_xor(y1, 32, 64);
  y2 += __shfl_xor(y2, 32, 64); y3 += __shfl_xor(y3, 32, 64);
  if (half == 0) {
    float inv0 = 1.0f / fmaxf((float)d0, 1.0f);
    float inv1 = 1.0f / fmaxf((float)d1, 1.0f);
    u16x4 o0, o1;
    o0[0] = f2b(x0 * inv0); o0[1] = f2b(x1 * inv0);
    o0[2] = f2b(x2 * inv0); o0[3] = f2b(x3 * inv0);
    o1[0] = f2b(y0 * inv1); o1[1] = f2b(y1 * inv1);
    o1[2] = f2b(y2 * inv1); o1[3] = f2b(y3 * inv1);
    *reinterpret_cast<u16x4*>(&out[(size_t)r0 * IN_ + col]) = o0;
    *reinterpret_cast<u16x4*>(&out[(size_t)r1 * IN_ + col]) = o1;
  }
}

// ---------------- layer-1 aggregate (bf16 source, F=256, ELL) ----------------
__global__ __launch_bounds__(256) void agg1(const u16* __restrict__ h,
                                            const int* __restrict__ ell,
                                            const int* __restrict__ cnt,
                                            u16* __restrict__ out, int M) {
  int wid = (blockIdx.x * 256 + threadIdx.x) >> 6;
  int lane = threadIdx.x & 63;
  if (wid >= M) return;
  const int d = cnt[wid];
  const size_t base = (size_t)wid * MAXDEG_;
  const int half = lane >> 5;
  const int col = (lane & 31) * 8;
  float a[8];
#pragma unroll
  for (int j = 0; j < 8; j++) a[j] = 0.f;
  for (int i = 0; i < d; i += 16) {
    int ids[8];
#pragma unroll
    for (int j = 0; j < 8; j++) {
      int k = i + 2 * j + half;
      k = k < d ? k : d - 1;
      ids[j] = ell[base + k];
    }
    u16x8 v[8];
#pragma unroll
    for (int j = 0; j < 8; j++)
      v[j] = *reinterpret_cast<const u16x8*>(&h[(size_t)ids[j] * HID_ + col]);
#pragma unroll
    for (int j = 0; j < 8; j++) {
      if (i + 2 * j + half < d) {
#pragma unroll
        for (int c = 0; c < 8; c++) a[c] += b2f(v[j][c]);
      }
    }
  }
#pragma unroll
  for (int c = 0; c < 8; c++) a[c] += __shfl_xor(a[c], 32, 64);
  if (half == 0) {
    float inv = 1.0f / fmaxf((float)d, 1.0f);
    u16x8 o;
#pragma unroll
    for (int c = 0; c < 8; c++) o[c] = f2b(a[c] * inv);
    *reinterpret_cast<u16x8*>(&out[(size_t)wid * HID_ + col]) = o;
  }
}

// ---------------- MFMA GEMM: out[Mx256] = relu([A0|A1] @ Bt^T + bias) ----------------
// BM=128, BN=256, BK=64; 512 threads = 8 waves (2m x 4n quadrants).
// A staged to LDS (swizzled); B read DIRECTLY from global Bt (L2-resident).
template <int KSELF, bool A0F32>
__global__ __launch_bounds__(512) void sage_gemm_mfma(
    const void* __restrict__ A0v, const u16* __restrict__ A1,
    const u16* __restrict__ Bt, const float* __restrict__ bias,
    u16* __restrict__ outp, int M) {
  constexpr int KTOT = 2 * KSELF;
  __shared__ u16 As[128 * 64];   // [m][k], XOR-swizzled, 16 KB
  const int tid = threadIdx.x;
  const int lane = tid & 63;
  const int w = tid >> 6;
  const int wm = w >> 2;
  const int wn = w & 3;
  const int m0 = blockIdx.x * 128;

  f32x4 acc[4][4];
#pragma unroll
  for (int m = 0; m < 4; m++)
#pragma unroll
    for (int n = 0; n < 4; n++) acc[m][n] = f32x4{0.f, 0.f, 0.f, 0.f};

  for (int kt = 0; kt < KTOT; kt += 64) {
    if (A0F32 && kt < KSELF) {
      const float* A0 = (const float*)A0v;
#pragma unroll
      for (int i = 0; i < 4; i++) {
        int e = tid + i * 512;
        int row = e >> 4;
        int c = (e & 15) * 4;
        int rowg = m0 + row; if (rowg >= M) rowg = M - 1;
        float4 v = *reinterpret_cast<const float4*>(&A0[(size_t)rowg * KSELF + kt + c]);
        u32 p0 = (u32)f2b(v.x) | ((u32)f2b(v.y) << 16);
        u32 p1 = (u32)f2b(v.z) | ((u32)f2b(v.w) << 16);
        int byt = ((row * 64 + c) * 2) ^ ((row & 7) << 4);
        u32* dp = reinterpret_cast<u32*>(reinterpret_cast<char*>(As) + byt);
        dp[0] = p0; dp[1] = p1;
      }
    } else {
      const u16* src; int ksrc;
      if (!A0F32 && kt < KSELF) { src = (const u16*)A0v; ksrc = kt; }
      else                      { src = A1;              ksrc = kt - KSELF; }
#pragma unroll
      for (int i = 0; i < 2; i++) {
        int e = tid + i * 512;
        int row = e >> 3;
        int ch = e & 7;
        int rowg = m0 + row; if (rowg >= M) rowg = M - 1;
        u16x8 v = *reinterpret_cast<const u16x8*>(&src[(size_t)rowg * KSELF + ksrc + ch * 8]);
        int byt = ((row * 64 + ch * 8) * 2) ^ ((row & 7) << 4);
        *reinterpret_cast<u16x8*>(reinterpret_cast<char*>(As) + byt) = v;
      }
    }
    __syncthreads();
#pragma unroll
    for (int kk = 0; kk < 64; kk += 32) {
      const int ksl = kk + (lane >> 4) * 8;
      b16x8 a[4], b[4];
#pragma unroll
      for (int n = 0; n < 4; n++) {
        int nrow = wn * 64 + n * 16 + (lane & 15);
        b[n] = *reinterpret_cast<const b16x8*>(&Bt[(size_t)nrow * KTOT + kt + ksl]);
      }
#pragma unroll
      for (int m = 0; m < 4; m++) {
        int row = wm * 64 + m * 16 + (lane & 15);
        int byt = (row * 128 + ksl * 2) ^ ((row & 7) << 4);
        a[m] = *reinterpret_cast<const b16x8*>(reinterpret_cast<const char*>(As) + byt);
      }
#pragma unroll
      for (int m = 0; m < 4; m++)
#pragma unroll
        for (int n = 0; n < 4; n++)
          acc[m][n] = __builtin_amdgcn_mfma_f32_16x16x32_bf16(a[m], b[n], acc[m][n], 0, 0, 0);
    }
    __syncthreads();
  }
  float bv[4];
#pragma unroll
  for (int n = 0; n < 4; n++) bv[n] = bias[wn * 64 + n * 16 + (lane & 15)];
#pragma unroll
  for (int m = 0; m < 4; m++) {
    int rowb = m0 + wm * 64 + m * 16 + ((lane >> 4) << 2);
#pragma unroll
    for (int r = 0; r < 4; r++) {
      int row = rowb + r;
      if (row < M) {
#pragma unroll
        for (int n = 0; n < 4; n++) {
          float v = acc[m][n][r] + bv[n];
          v = fmaxf(v, 0.0f);
          outp[(size_t)row * 256 + wn * 64 + n * 16 + (lane & 15)] = f2b(v);
        }
      }
    }
  }
}

// ---------------- fused final layer: gather + GEMM (M=2048, K=512, N=47) ----------------
__global__ __launch_bounds__(64) void fused_out(
    const u16* __restrict__ h, const int* __restrict__ ell,
    const int* __restrict__ cnt, const float* __restrict__ Ws,
    const float* __restrict__ Wn, const float* __restrict__ bias,
    float* __restrict__ out) {
  __shared__ float As[512];
  const int row = blockIdx.x;
  const int t = threadIdx.x;
  u16x4 a = *reinterpret_cast<const u16x4*>(&h[(size_t)row * 256 + t * 4]);
#pragma unroll
  for (int j = 0; j < 4; j++) As[t * 4 + j] = b2f(a[j]);
  const int d = cnt[row];
  const size_t base = (size_t)row * MAXDEG_;
  float s0 = 0.f, s1 = 0.f, s2 = 0.f, s3 = 0.f;
  for (int i = 0; i < d; i += 4) {
    int k1 = (i + 1 < d) ? i + 1 : i;
    int k2 = (i + 2 < d) ? i + 2 : i;
    int k3 = (i + 3 < d) ? i + 3 : i;
    int e0 = ell[base + i], e1 = ell[base + k1], e2 = ell[base + k2], e3 = ell[base + k3];
    u16x4 v0 = *reinterpret_cast<const u16x4*>(&h[(size_t)e0 * 256 + t * 4]);
    u16x4 v1 = *reinterpret_cast<const u16x4*>(&h[(size_t)e1 * 256 + t * 4]);
    u16x4 v2 = *reinterpret_cast<const u16x4*>(&h[(size_t)e2 * 256 + t * 4]);
    u16x4 v3 = *reinterpret_cast<const u16x4*>(&h[(size_t)e3 * 256 + t * 4]);
    s0 += b2f(v0[0]); s1 += b2f(v0[1]); s2 += b2f(v0[2]); s3 += b2f(v0[3]);
    if (i + 1 < d) { s0 += b2f(v1[0]); s1 += b2f(v1[1]); s2 += b2f(v1[2]); s3 += b2f(v1[3]); }
    if (i + 2 < d) { s0 += b2f(v2[0]); s1 += b2f(v2[1]); s2 += b2f(v2[2]); s3 += b2f(v2[3]); }
    if (i + 3 < d) { s0 += b2f(v3[0]); s1 += b2f(v3[1]); s2 += b2f(v3[2]); s3 += b2f(v3[3]); }
  }
  float inv = 1.0f / fmaxf((float)d, 1.0f);
  As[256 + t * 4 + 0] = s0 * inv;
  As[256 + t * 4 + 1] = s1 * inv;
  As[256 + t * 4 + 2] = s2 * inv;
  As[256 + t * 4 + 3] = s3 * inv;
  __syncthreads();
  if (t < OUT_) {
    float s = bias[t];
#pragma unroll 8
    for (int k = 0; k < 256; k++) s = fmaf(As[k], Ws[k * 47 + t], s);
#pragma unroll 8
    for (int k = 0; k < 256; k++) s = fmaf(As[256 + k], Wn[k * 47 + t], s);
    out[(size_t)row * 47 + t] = s;
  }
}

// ---------------- host driver ----------------
extern "C" void kernel_launch(void* const* d_in, const int* in_sizes, int n_in,
                              void* d_out, int out_size, void* d_ws, size_t ws_size,
                              hipStream_t stream) {
  const float* x      = (const float*)d_in[0];
  const int*   src0   = (const int*)d_in[1];
  const int*   dst0   = (const int*)d_in[2];
  const int*   src1   = (const int*)d_in[3];
  const int*   dst1   = (const int*)d_in[4];
  const int*   src2   = (const int*)d_in[5];
  const int*   dst2   = (const int*)d_in[6];
  const float* Wself0 = (const float*)d_in[7];
  const float* Wneigh0= (const float*)d_in[8];
  const float* b0     = (const float*)d_in[9];
  const float* Wself1 = (const float*)d_in[10];
  const float* Wneigh1= (const float*)d_in[11];
  const float* b1     = (const float*)d_in[12];
  const float* Wself2 = (const float*)d_in[13];
  const float* Wneigh2= (const float*)d_in[14];
  const float* b2     = (const float*)d_in[15];

  int* wsi   = (int*)d_ws;
  int* cnt   = wsi + OFF_CNT;
  int* ell   = wsi + OFF_ELL;
  u16* Bt0   = (u16*)(wsi + OFF_BT0);
  u16* Bt1   = (u16*)(wsi + OFF_BT1);
  u16* HN0   = (u16*)(wsi + OFF_HN0);
  u16* H1    = (u16*)(wsi + OFF_H1);
  u16* HN1   = (u16*)(wsi + OFF_HN1);
  u16* H2    = (u16*)(wsi + OFF_H2);
  float* out = (float*)d_out;

  // zero degree counts only
  hipMemsetAsync(cnt, 0, (size_t)NTOT_ * 4, stream);

  // one-pass ELL build (all 3 layers) + weight packs
  {
    int total = ETOT_ + 256 * 256 + 256 * 512;
    prep<<<(total + 255) / 256, 256, 0, stream>>>(
        src0, dst0, src1, dst1, src2, dst2,
        Wself0, Wneigh0, Wself1, Wneigh1, cnt, ell, Bt0, Bt1);
  }

  // ---- layer 0 ----
  agg0_pair<<<(N1_ / 2 + 3) / 4, 256, 0, stream>>>(x, ell, cnt, HN0, N1_);
  sage_gemm_mfma<IN_, true><<<(N1_ + 127) / 128, 512, 0, stream>>>(
      x, HN0, Bt0, b0, H1, N1_);

  // ---- layer 1 ----
  agg1<<<(N2_ + 3) / 4, 256, 0, stream>>>(
      H1, ell + (size_t)N1_ * MAXDEG_, cnt + N1_, HN1, N2_);
  sage_gemm_mfma<HID_, false><<<(N2_ + 127) / 128, 512, 0, stream>>>(
      H1, HN1, Bt1, b1, H2, N2_);

  // ---- layer 2 (fused gather + output GEMM) ----
  fused_out<<<N3_, 64, 0, stream>>>(
      H2, ell + (size_t)(N1_ + N2_) * MAXDEG_, cnt + N1_ + N2_,
      Wself2, Wneigh2, b2, out);
}

// Round 9
// 508.037 us; speedup vs baseline: 1.1823x; 1.1823x over previous
//
#include <hip/hip_runtime.h>

#define N0_ 1000000
#define N1_ 200000
#define N2_ 20000
#define N3_ 2048
#define E0_ 2000000
#define E1_ 200000
#define E2_ 20480
#define IN_ 128
#define HID_ 256
#define OUT_ 47

#define NTOT_ (N1_ + N2_ + N3_)          // 222048
#define ETOT_ (E0_ + E1_ + E2_)          // 2220480
#define MAXDEG_ 48                        // Poisson(10): P(deg>=48) ~ 1e-18

typedef unsigned short u16;
typedef unsigned int u32;
typedef __attribute__((ext_vector_type(8))) short b16x8;
typedef __attribute__((ext_vector_type(4))) float f32x4;
typedef __attribute__((ext_vector_type(4))) u16 u16x4;
typedef __attribute__((ext_vector_type(8))) u16 u16x8;

__device__ __forceinline__ u16 f2b(float f) {  // RNE fp32->bf16
  u32 u = __builtin_bit_cast(u32, f);
  return (u16)((u + 0x7FFFu + ((u >> 16) & 1u)) >> 16);
}
__device__ __forceinline__ float b2f(u16 b) {
  return __builtin_bit_cast(float, (u32)b << 16);
}

// ---------------- workspace layout (4-byte words) ----------------
static constexpr size_t OFF_CNT = 0;                       // NTOT (degree counts)
static constexpr size_t OFF_ELL = 222080;                  // NTOT*48 = 10658304
static constexpr size_t OFF_BT0 = 10880384;                // 32768  (256n x 256k bf16)
static constexpr size_t OFF_BT1 = 10913152;                // 65536  (256n x 512k bf16)
static constexpr size_t OFF_HN0 = 10978688;                // 12800000 (200000x128 bf16)
static constexpr size_t OFF_H1  = 23778688;                // 25600000 (200000x256 bf16)
static constexpr size_t OFF_HN1 = 49378688;                // 2560000  (20000x256 bf16)
static constexpr size_t OFF_H2  = 51938688;                // 2560000
// end: 54,498,688 words = 218 MB

// ---------------- one-pass ELL build + weight packs ----------------
__global__ __launch_bounds__(256) void prep(
    const int* __restrict__ src0, const int* __restrict__ dst0,
    const int* __restrict__ src1, const int* __restrict__ dst1,
    const int* __restrict__ src2, const int* __restrict__ dst2,
    const float* __restrict__ Ws0, const float* __restrict__ Wn0,
    const float* __restrict__ Ws1, const float* __restrict__ Wn1,
    int* __restrict__ cnt, int* __restrict__ ell,
    u16* __restrict__ Bt0, u16* __restrict__ Bt1) {
  int t = blockIdx.x * 256 + threadIdx.x;
  if (t < ETOT_) {
    int s, node;
    if (t < E0_) { s = src0[t]; node = dst0[t]; }
    else if (t < E0_ + E1_) { s = src1[t - E0_]; node = N1_ + dst1[t - E0_]; }
    else { s = src2[t - E0_ - E1_]; node = N1_ + N2_ + dst2[t - E0_ - E1_]; }
    int slot = atomicAdd(&cnt[node], 1);
    if (slot < MAXDEG_) ell[(size_t)node * MAXDEG_ + slot] = s;
    return;
  }
  t -= ETOT_;
  if (t < 256 * 256) {  // Bt0: [n][k], KT=256
    int n = t & 255, k = t >> 8;
    float v = (k < IN_) ? Ws0[(size_t)k * 256 + n] : Wn0[(size_t)(k - IN_) * 256 + n];
    Bt0[(size_t)n * 256 + k] = f2b(v);
    return;
  }
  t -= 256 * 256;
  if (t < 256 * 512) {  // Bt1: [n][k], KT=512
    int n = t & 255, k = t >> 8;
    float v = (k < HID_) ? Ws1[(size_t)k * 256 + n] : Wn1[(size_t)(k - HID_) * 256 + n];
    Bt1[(size_t)n * 512 + k] = f2b(v);
  }
}

// ---------------- layer-0 aggregate: fp32 source, F=128, one row/wave ----------------
// 16 edges in flight: lanes 0-31 even edges, 32-63 odd edges, each lane a 16B slice.
__global__ __launch_bounds__(256) void agg0(const float* __restrict__ h,
                                            const int* __restrict__ ell,
                                            const int* __restrict__ cnt,
                                            u16* __restrict__ out, int M) {
  int wid = (blockIdx.x * 256 + threadIdx.x) >> 6;
  int lane = threadIdx.x & 63;
  if (wid >= M) return;
  const int d = cnt[wid];
  const size_t base = (size_t)wid * MAXDEG_;
  const int half = lane >> 5;        // 0: even edges, 1: odd edges
  const int col = (lane & 31) * 4;   // fp32 col
  float a0 = 0.f, a1 = 0.f, a2 = 0.f, a3 = 0.f;
  for (int i = 0; i < d; i += 16) {
    int ids[8];
#pragma unroll
    for (int j = 0; j < 8; j++) {
      int k = i + 2 * j + half;
      k = k < d ? k : d - 1;
      ids[j] = ell[base + k];
    }
    float4 v[8];
#pragma unroll
    for (int j = 0; j < 8; j++)
      v[j] = *reinterpret_cast<const float4*>(&h[(size_t)ids[j] * IN_ + col]);
#pragma unroll
    for (int j = 0; j < 8; j++) {
      if (i + 2 * j + half < d) {
        a0 += v[j].x; a1 += v[j].y; a2 += v[j].z; a3 += v[j].w;
      }
    }
  }
  a0 += __shfl_xor(a0, 32, 64);
  a1 += __shfl_xor(a1, 32, 64);
  a2 += __shfl_xor(a2, 32, 64);
  a3 += __shfl_xor(a3, 32, 64);
  if (half == 0) {
    float inv = 1.0f / fmaxf((float)d, 1.0f);
    u16x4 o;
    o[0] = f2b(a0 * inv); o[1] = f2b(a1 * inv);
    o[2] = f2b(a2 * inv); o[3] = f2b(a3 * inv);
    *reinterpret_cast<u16x4*>(&out[(size_t)wid * IN_ + col]) = o;
  }
}

// ---------------- layer-1 aggregate (bf16 source, F=256, ELL) ----------------
__global__ __launch_bounds__(256) void agg1(const u16* __restrict__ h,
                                            const int* __restrict__ ell,
                                            const int* __restrict__ cnt,
                                            u16* __restrict__ out, int M) {
  int wid = (blockIdx.x * 256 + threadIdx.x) >> 6;
  int lane = threadIdx.x & 63;
  if (wid >= M) return;
  const int d = cnt[wid];
  const size_t base = (size_t)wid * MAXDEG_;
  const int half = lane >> 5;
  const int col = (lane & 31) * 8;
  float a[8];
#pragma unroll
  for (int j = 0; j < 8; j++) a[j] = 0.f;
  for (int i = 0; i < d; i += 16) {
    int ids[8];
#pragma unroll
    for (int j = 0; j < 8; j++) {
      int k = i + 2 * j + half;
      k = k < d ? k : d - 1;
      ids[j] = ell[base + k];
    }
    u16x8 v[8];
#pragma unroll
    for (int j = 0; j < 8; j++)
      v[j] = *reinterpret_cast<const u16x8*>(&h[(size_t)ids[j] * HID_ + col]);
#pragma unroll
    for (int j = 0; j < 8; j++) {
      if (i + 2 * j + half < d) {
#pragma unroll
        for (int c = 0; c < 8; c++) a[c] += b2f(v[j][c]);
      }
    }
  }
#pragma unroll
  for (int c = 0; c < 8; c++) a[c] += __shfl_xor(a[c], 32, 64);
  if (half == 0) {
    float inv = 1.0f / fmaxf((float)d, 1.0f);
    u16x8 o;
#pragma unroll
    for (int c = 0; c < 8; c++) o[c] = f2b(a[c] * inv);
    *reinterpret_cast<u16x8*>(&out[(size_t)wid * HID_ + col]) = o;
  }
}

// ---------------- MFMA GEMM: out[Mx256] = relu([A0|A1] @ Bt^T + bias) ----------------
// BM=128, BN=256, BK=64; 512 threads = 8 waves (2m x 4n quadrants).
// A staged to LDS (swizzled); B read DIRECTLY from global Bt (L2-resident).
template <int KSELF, bool A0F32>
__global__ __launch_bounds__(512) void sage_gemm_mfma(
    const void* __restrict__ A0v, const u16* __restrict__ A1,
    const u16* __restrict__ Bt, const float* __restrict__ bias,
    u16* __restrict__ outp, int M) {
  constexpr int KTOT = 2 * KSELF;
  __shared__ u16 As[128 * 64];   // [m][k], XOR-swizzled, 16 KB
  const int tid = threadIdx.x;
  const int lane = tid & 63;
  const int w = tid >> 6;
  const int wm = w >> 2;
  const int wn = w & 3;
  const int m0 = blockIdx.x * 128;

  f32x4 acc[4][4];
#pragma unroll
  for (int m = 0; m < 4; m++)
#pragma unroll
    for (int n = 0; n < 4; n++) acc[m][n] = f32x4{0.f, 0.f, 0.f, 0.f};

  for (int kt = 0; kt < KTOT; kt += 64) {
    if (A0F32 && kt < KSELF) {
      const float* A0 = (const float*)A0v;
#pragma unroll
      for (int i = 0; i < 4; i++) {
        int e = tid + i * 512;
        int row = e >> 4;
        int c = (e & 15) * 4;
        int rowg = m0 + row; if (rowg >= M) rowg = M - 1;
        float4 v = *reinterpret_cast<const float4*>(&A0[(size_t)rowg * KSELF + kt + c]);
        u32 p0 = (u32)f2b(v.x) | ((u32)f2b(v.y) << 16);
        u32 p1 = (u32)f2b(v.z) | ((u32)f2b(v.w) << 16);
        int byt = ((row * 64 + c) * 2) ^ ((row & 7) << 4);
        u32* dp = reinterpret_cast<u32*>(reinterpret_cast<char*>(As) + byt);
        dp[0] = p0; dp[1] = p1;
      }
    } else {
      const u16* src; int ksrc;
      if (!A0F32 && kt < KSELF) { src = (const u16*)A0v; ksrc = kt; }
      else                      { src = A1;              ksrc = kt - KSELF; }
#pragma unroll
      for (int i = 0; i < 2; i++) {
        int e = tid + i * 512;
        int row = e >> 3;
        int ch = e & 7;
        int rowg = m0 + row; if (rowg >= M) rowg = M - 1;
        u16x8 v = *reinterpret_cast<const u16x8*>(&src[(size_t)rowg * KSELF + ksrc + ch * 8]);
        int byt = ((row * 64 + ch * 8) * 2) ^ ((row & 7) << 4);
        *reinterpret_cast<u16x8*>(reinterpret_cast<char*>(As) + byt) = v;
      }
    }
    __syncthreads();
#pragma unroll
    for (int kk = 0; kk < 64; kk += 32) {
      const int ksl = kk + (lane >> 4) * 8;
      b16x8 a[4], b[4];
#pragma unroll
      for (int n = 0; n < 4; n++) {
        int nrow = wn * 64 + n * 16 + (lane & 15);
        b[n] = *reinterpret_cast<const b16x8*>(&Bt[(size_t)nrow * KTOT + kt + ksl]);
      }
#pragma unroll
      for (int m = 0; m < 4; m++) {
        int row = wm * 64 + m * 16 + (lane & 15);
        int byt = (row * 128 + ksl * 2) ^ ((row & 7) << 4);
        a[m] = *reinterpret_cast<const b16x8*>(reinterpret_cast<const char*>(As) + byt);
      }
#pragma unroll
      for (int m = 0; m < 4; m++)
#pragma unroll
        for (int n = 0; n < 4; n++)
          acc[m][n] = __builtin_amdgcn_mfma_f32_16x16x32_bf16(a[m], b[n], acc[m][n], 0, 0, 0);
    }
    __syncthreads();
  }
  float bv[4];
#pragma unroll
  for (int n = 0; n < 4; n++) bv[n] = bias[wn * 64 + n * 16 + (lane & 15)];
#pragma unroll
  for (int m = 0; m < 4; m++) {
    int rowb = m0 + wm * 64 + m * 16 + ((lane >> 4) << 2);
#pragma unroll
    for (int r = 0; r < 4; r++) {
      int row = rowb + r;
      if (row < M) {
#pragma unroll
        for (int n = 0; n < 4; n++) {
          float v = acc[m][n][r] + bv[n];
          v = fmaxf(v, 0.0f);
          outp[(size_t)row * 256 + wn * 64 + n * 16 + (lane & 15)] = f2b(v);
        }
      }
    }
  }
}

// ---------------- fused final layer: gather + GEMM (M=2048, K=512, N=47) ----------------
__global__ __launch_bounds__(64) void fused_out(
    const u16* __restrict__ h, const int* __restrict__ ell,
    const int* __restrict__ cnt, const float* __restrict__ Ws,
    const float* __restrict__ Wn, const float* __restrict__ bias,
    float* __restrict__ out) {
  __shared__ float As[512];
  const int row = blockIdx.x;
  const int t = threadIdx.x;
  u16x4 a = *reinterpret_cast<const u16x4*>(&h[(size_t)row * 256 + t * 4]);
#pragma unroll
  for (int j = 0; j < 4; j++) As[t * 4 + j] = b2f(a[j]);
  const int d = cnt[row];
  const size_t base = (size_t)row * MAXDEG_;
  float s0 = 0.f, s1 = 0.f, s2 = 0.f, s3 = 0.f;
  for (int i = 0; i < d; i += 4) {
    int k1 = (i + 1 < d) ? i + 1 : i;
    int k2 = (i + 2 < d) ? i + 2 : i;
    int k3 = (i + 3 < d) ? i + 3 : i;
    int e0 = ell[base + i], e1 = ell[base + k1], e2 = ell[base + k2], e3 = ell[base + k3];
    u16x4 v0 = *reinterpret_cast<const u16x4*>(&h[(size_t)e0 * 256 + t * 4]);
    u16x4 v1 = *reinterpret_cast<const u16x4*>(&h[(size_t)e1 * 256 + t * 4]);
    u16x4 v2 = *reinterpret_cast<const u16x4*>(&h[(size_t)e2 * 256 + t * 4]);
    u16x4 v3 = *reinterpret_cast<const u16x4*>(&h[(size_t)e3 * 256 + t * 4]);
    s0 += b2f(v0[0]); s1 += b2f(v0[1]); s2 += b2f(v0[2]); s3 += b2f(v0[3]);
    if (i + 1 < d) { s0 += b2f(v1[0]); s1 += b2f(v1[1]); s2 += b2f(v1[2]); s3 += b2f(v1[3]); }
    if (i + 2 < d) { s0 += b2f(v2[0]); s1 += b2f(v2[1]); s2 += b2f(v2[2]); s3 += b2f(v2[3]); }
    if (i + 3 < d) { s0 += b2f(v3[0]); s1 += b2f(v3[1]); s2 += b2f(v3[2]); s3 += b2f(v3[3]); }
  }
  float inv = 1.0f / fmaxf((float)d, 1.0f);
  As[256 + t * 4 + 0] = s0 * inv;
  As[256 + t * 4 + 1] = s1 * inv;
  As[256 + t * 4 + 2] = s2 * inv;
  As[256 + t * 4 + 3] = s3 * inv;
  __syncthreads();
  if (t < OUT_) {
    float s = bias[t];
#pragma unroll 8
    for (int k = 0; k < 256; k++) s = fmaf(As[k], Ws[k * 47 + t], s);
#pragma unroll 8
    for (int k = 0; k < 256; k++) s = fmaf(As[256 + k], Wn[k * 47 + t], s);
    out[(size_t)row * 47 + t] = s;
  }
}

// ---------------- host driver ----------------
extern "C" void kernel_launch(void* const* d_in, const int* in_sizes, int n_in,
                              void* d_out, int out_size, void* d_ws, size_t ws_size,
                              hipStream_t stream) {
  const float* x      = (const float*)d_in[0];
  const int*   src0   = (const int*)d_in[1];
  const int*   dst0   = (const int*)d_in[2];
  const int*   src1   = (const int*)d_in[3];
  const int*   dst1   = (const int*)d_in[4];
  const int*   src2   = (const int*)d_in[5];
  const int*   dst2   = (const int*)d_in[6];
  const float* Wself0 = (const float*)d_in[7];
  const float* Wneigh0= (const float*)d_in[8];
  const float* b0     = (const float*)d_in[9];
  const float* Wself1 = (const float*)d_in[10];
  const float* Wneigh1= (const float*)d_in[11];
  const float* b1     = (const float*)d_in[12];
  const float* Wself2 = (const float*)d_in[13];
  const float* Wneigh2= (const float*)d_in[14];
  const float* b2     = (const float*)d_in[15];

  int* wsi   = (int*)d_ws;
  int* cnt   = wsi + OFF_CNT;
  int* ell   = wsi + OFF_ELL;
  u16* Bt0   = (u16*)(wsi + OFF_BT0);
  u16* Bt1   = (u16*)(wsi + OFF_BT1);
  u16* HN0   = (u16*)(wsi + OFF_HN0);
  u16* H1    = (u16*)(wsi + OFF_H1);
  u16* HN1   = (u16*)(wsi + OFF_HN1);
  u16* H2    = (u16*)(wsi + OFF_H2);
  float* out = (float*)d_out;

  // zero degree counts only
  hipMemsetAsync(cnt, 0, (size_t)NTOT_ * 4, stream);

  // one-pass ELL build (all 3 layers) + weight packs
  {
    int total = ETOT_ + 256 * 256 + 256 * 512;
    prep<<<(total + 255) / 256, 256, 0, stream>>>(
        src0, dst0, src1, dst1, src2, dst2,
        Wself0, Wneigh0, Wself1, Wneigh1, cnt, ell, Bt0, Bt1);
  }

  // ---- layer 0 ----
  agg0<<<(N1_ + 3) / 4, 256, 0, stream>>>(x, ell, cnt, HN0, N1_);
  sage_gemm_mfma<IN_, true><<<(N1_ + 127) / 128, 512, 0, stream>>>(
      x, HN0, Bt0, b0, H1, N1_);

  // ---- layer 1 ----
  agg1<<<(N2_ + 3) / 4, 256, 0, stream>>>(
      H1, ell + (size_t)N1_ * MAXDEG_, cnt + N1_, HN1, N2_);
  sage_gemm_mfma<HID_, false><<<(N2_ + 127) / 128, 512, 0, stream>>>(
      H1, HN1, Bt1, b1, H2, N2_);

  // ---- layer 2 (fused gather + output GEMM) ----
  fused_out<<<N3_, 64, 0, stream>>>(
      H2, ell + (size_t)(N1_ + N2_) * MAXDEG_, cnt + N1_ + N2_,
      Wself2, Wneigh2, b2, out);
}